// Round 1
// baseline (2637.418 us; speedup 1.0000x reference)
//
#include <hip/hip_runtime.h>
#include <math.h>

// GatedGraphXBias: E=12 edge types, T=2048, H=64, IN=128, 10 iterations.
// Round 1: correct fp32 baseline, tiled vector-ALU bmm (no fp32 MFMA on CDNA4).

constexpr int T   = 2048;
constexpr int H   = 64;
constexpr int E   = 12;
constexpr int FIN = 128;
constexpr int K3  = 192;   // 3*H
constexpr int ITER = 10;

__device__ __forceinline__ float sigmoidf_(float x) {
    return 1.0f / (1.0f + __expf(-x));
}

// constv[k] = sum_{e,h} ba[e,h]*W[e,h,k] + E*bw[k]
__global__ void const_kernel(const float* __restrict__ ba,
                             const float* __restrict__ W,
                             const float* __restrict__ bw,
                             float* __restrict__ constv) {
    int k = blockIdx.x * blockDim.x + threadIdx.x;
    if (k >= K3) return;
    float s = (float)E * bw[k];
    for (int eh = 0; eh < E * H; ++eh)
        s += ba[eh] * W[(size_t)eh * K3 + k];
    constv[k] = s;
}

// base[t,k] = constv[k] + sum_j x[t,j]*iw[j,k]   (iteration-invariant, hoisted)
__global__ __launch_bounds__(256) void base_kernel(const float* __restrict__ x,
                                                   const float* __restrict__ iw,
                                                   const float* __restrict__ constv,
                                                   float* __restrict__ base) {
    int idx = blockIdx.x * 256 + threadIdx.x;     // T*K3 = 1536*256 exactly
    int t = idx / K3, k = idx % K3;
    float acc = constv[k];
    const float* xr = x + (size_t)t * FIN;
    for (int j = 0; j < FIN; ++j)
        acc = fmaf(xr[j], iw[(size_t)j * K3 + k], acc);
    base[idx] = acc;
}

// P[e,t,h] = sum_s edge[e,s,t]*hbuf[s,h]
// grid (T/64, E), block 128. Per-thread 8x4 tile, BK=32.
constexpr int BMM_BM = 64;
constexpr int BMM_BK = 32;

__global__ __launch_bounds__(128) void bmm_kernel(const float* __restrict__ edge,
                                                  const float* __restrict__ hbuf,
                                                  float* __restrict__ P) {
    __shared__ float As[BMM_BK][68];   // [s][t], pad 68 to break store conflicts
    __shared__ float Bs[BMM_BK][68];   // [s][h]
    const int e  = blockIdx.y;
    const int t0 = blockIdx.x * BMM_BM;
    const int tid = threadIdx.x;
    const int ty = tid >> 4;           // 0..7 -> rows ty*8..+7
    const int tx = tid & 15;           // 0..15 -> cols tx*4..+3
    const float* eb = edge + (size_t)e * T * T;

    float acc[8][4];
    #pragma unroll
    for (int i = 0; i < 8; ++i)
        #pragma unroll
        for (int j = 0; j < 4; ++j) acc[i][j] = 0.0f;

    for (int s0 = 0; s0 < T; s0 += BMM_BK) {
        #pragma unroll
        for (int p = 0; p < 4; ++p) {
            int idx = tid + p * 128;
            int r = idx >> 4, c4 = (idx & 15) << 2;
            *reinterpret_cast<float4*>(&As[r][c4]) =
                *reinterpret_cast<const float4*>(eb + (size_t)(s0 + r) * T + t0 + c4);
            *reinterpret_cast<float4*>(&Bs[r][c4]) =
                *reinterpret_cast<const float4*>(hbuf + (size_t)(s0 + r) * H + c4);
        }
        __syncthreads();
        #pragma unroll
        for (int k = 0; k < BMM_BK; ++k) {
            float a[8], b[4];
            *reinterpret_cast<float4*>(&a[0]) = *reinterpret_cast<const float4*>(&As[k][ty * 8]);
            *reinterpret_cast<float4*>(&a[4]) = *reinterpret_cast<const float4*>(&As[k][ty * 8 + 4]);
            *reinterpret_cast<float4*>(&b[0]) = *reinterpret_cast<const float4*>(&Bs[k][tx * 4]);
            #pragma unroll
            for (int i = 0; i < 8; ++i)
                #pragma unroll
                for (int j = 0; j < 4; ++j)
                    acc[i][j] = fmaf(a[i], b[j], acc[i][j]);
        }
        __syncthreads();
    }
    float* pb = P + ((size_t)e * T + t0) * H;
    #pragma unroll
    for (int i = 0; i < 8; ++i) {
        float4 v = make_float4(acc[i][0], acc[i][1], acc[i][2], acc[i][3]);
        *reinterpret_cast<float4*>(pb + (size_t)(ty * 8 + i) * H + tx * 4) = v;
    }
}

// partial[e,t,k] = sum_h P[e,t,h]*W[e,h,k]
// grid (T/64, E), block 256. Per-thread 4x12 tile over [64 x 192].
__global__ __launch_bounds__(256) void proj_kernel(const float* __restrict__ P,
                                                   const float* __restrict__ W,
                                                   float* __restrict__ partial) {
    __shared__ float Ps[64][68];
    __shared__ float Ws[H][K3];
    const int e  = blockIdx.y;
    const int t0 = blockIdx.x * 64;
    const int tid = threadIdx.x;
    const float* pb = P + ((size_t)e * T + t0) * H;
    const float* wb = W + (size_t)e * H * K3;
    #pragma unroll
    for (int p = 0; p < 4; ++p) {
        int idx = tid + p * 256;
        int r = idx >> 4, c4 = (idx & 15) << 2;
        *reinterpret_cast<float4*>(&Ps[r][c4]) =
            *reinterpret_cast<const float4*>(pb + (size_t)r * H + c4);
    }
    #pragma unroll
    for (int p = 0; p < 12; ++p) {
        int idx = tid + p * 256;
        int r = idx / 48, c4 = (idx % 48) << 2;
        *reinterpret_cast<float4*>(&Ws[r][c4]) =
            *reinterpret_cast<const float4*>(wb + (size_t)r * K3 + c4);
    }
    __syncthreads();
    const int ty = tid >> 4;    // rows ty*4..+3
    const int tx = tid & 15;    // cols tx*12..+11
    float acc[4][12];
    #pragma unroll
    for (int i = 0; i < 4; ++i)
        #pragma unroll
        for (int c = 0; c < 12; ++c) acc[i][c] = 0.0f;

    for (int h = 0; h < H; ++h) {
        float a[4], b[12];
        #pragma unroll
        for (int i = 0; i < 4; ++i) a[i] = Ps[ty * 4 + i][h];
        *reinterpret_cast<float4*>(&b[0]) = *reinterpret_cast<const float4*>(&Ws[h][tx * 12]);
        *reinterpret_cast<float4*>(&b[4]) = *reinterpret_cast<const float4*>(&Ws[h][tx * 12 + 4]);
        *reinterpret_cast<float4*>(&b[8]) = *reinterpret_cast<const float4*>(&Ws[h][tx * 12 + 8]);
        #pragma unroll
        for (int i = 0; i < 4; ++i)
            #pragma unroll
            for (int c = 0; c < 12; ++c)
                acc[i][c] = fmaf(a[i], b[c], acc[i][c]);
    }
    float* ob = partial + ((size_t)e * T + t0) * K3;
    #pragma unroll
    for (int i = 0; i < 4; ++i) {
        float* orow = ob + (size_t)(ty * 4 + i) * K3 + tx * 12;
        *reinterpret_cast<float4*>(orow)     = make_float4(acc[i][0], acc[i][1], acc[i][2],  acc[i][3]);
        *reinterpret_cast<float4*>(orow + 4) = make_float4(acc[i][4], acc[i][5], acc[i][6],  acc[i][7]);
        *reinterpret_cast<float4*>(orow + 8) = make_float4(acc[i][8], acc[i][9], acc[i][10], acc[i][11]);
    }
}

// GRU update, h in place. grid T/16, block 256 (16 rows x 16 col-groups of 4).
__global__ __launch_bounds__(256) void gru_kernel(float* __restrict__ hbuf,
                                                  const float* __restrict__ partial,
                                                  const float* __restrict__ base,
                                                  const float* __restrict__ uzur,
                                                  const float* __restrict__ uhm) {
    __shared__ float Uzr[H][2 * H];    // 32 KB
    __shared__ float Uh[H][H];         // 16 KB
    __shared__ float hrow[16][68];
    __shared__ float rh[16][68];
    const int t0 = blockIdx.x * 16;
    const int tid = threadIdx.x;
    #pragma unroll
    for (int p = 0; p < 8; ++p) {
        int idx = tid + p * 256;
        int r = idx >> 5, c4 = (idx & 31) << 2;
        *reinterpret_cast<float4*>(&Uzr[r][c4]) =
            *reinterpret_cast<const float4*>(uzur + (size_t)r * 2 * H + c4);
    }
    #pragma unroll
    for (int p = 0; p < 4; ++p) {
        int idx = tid + p * 256;
        int r = idx >> 4, c4 = (idx & 15) << 2;
        *reinterpret_cast<float4*>(&Uh[r][c4]) =
            *reinterpret_cast<const float4*>(uhm + (size_t)r * H + c4);
    }
    {
        int r = tid >> 4, c4 = (tid & 15) << 2;
        *reinterpret_cast<float4*>(&hrow[r][c4]) =
            *reinterpret_cast<const float4*>(hbuf + (size_t)(t0 + r) * H + c4);
    }
    __syncthreads();
    const int row = tid >> 4, cg = tid & 15;
    const int t = t0 + row, j0 = cg * 4;

    float az[4], ar[4], ah[4];
    const float* bp = base + (size_t)t * K3;
    {
        float4 b0 = *reinterpret_cast<const float4*>(bp + j0);
        float4 b1 = *reinterpret_cast<const float4*>(bp + 64 + j0);
        float4 b2 = *reinterpret_cast<const float4*>(bp + 128 + j0);
        az[0]=b0.x; az[1]=b0.y; az[2]=b0.z; az[3]=b0.w;
        ar[0]=b1.x; ar[1]=b1.y; ar[2]=b1.z; ar[3]=b1.w;
        ah[0]=b2.x; ah[1]=b2.y; ah[2]=b2.z; ah[3]=b2.w;
    }
    #pragma unroll
    for (int e = 0; e < E; ++e) {
        const float* pp = partial + ((size_t)e * T + t) * K3;
        float4 v0 = *reinterpret_cast<const float4*>(pp + j0);
        float4 v1 = *reinterpret_cast<const float4*>(pp + 64 + j0);
        float4 v2 = *reinterpret_cast<const float4*>(pp + 128 + j0);
        az[0]+=v0.x; az[1]+=v0.y; az[2]+=v0.z; az[3]+=v0.w;
        ar[0]+=v1.x; ar[1]+=v1.y; ar[2]+=v1.z; ar[3]+=v1.w;
        ah[0]+=v2.x; ah[1]+=v2.y; ah[2]+=v2.z; ah[3]+=v2.w;
    }
    float hv[4];
    #pragma unroll
    for (int c = 0; c < 4; ++c) hv[c] = hrow[row][j0 + c];

    float uz[4] = {0,0,0,0}, ur[4] = {0,0,0,0};
    for (int hh = 0; hh < H; ++hh) {
        float hs = hrow[row][hh];
        #pragma unroll
        for (int c = 0; c < 4; ++c) {
            uz[c] = fmaf(hs, Uzr[hh][j0 + c], uz[c]);
            ur[c] = fmaf(hs, Uzr[hh][64 + j0 + c], ur[c]);
        }
    }
    float z[4], rr[4];
    #pragma unroll
    for (int c = 0; c < 4; ++c) {
        z[c]  = sigmoidf_(az[c] + uz[c]);
        rr[c] = sigmoidf_(ar[c] + ur[c]);
        rh[row][j0 + c] = rr[c] * hv[c];
    }
    __syncthreads();
    float uht[4] = {0,0,0,0};
    for (int hh = 0; hh < H; ++hh) {
        float rs = rh[row][hh];
        #pragma unroll
        for (int c = 0; c < 4; ++c)
            uht[c] = fmaf(rs, Uh[hh][j0 + c], uht[c]);
    }
    float hn[4];
    #pragma unroll
    for (int c = 0; c < 4; ++c) {
        float ht = tanhf(ah[c] + uht[c]);
        hn[c] = (1.0f - z[c]) * hv[c] + z[c] * ht;
    }
    *reinterpret_cast<float4*>(hbuf + (size_t)t * H + j0) =
        make_float4(hn[0], hn[1], hn[2], hn[3]);
}

extern "C" void kernel_launch(void* const* d_in, const int* in_sizes, int n_in,
                              void* d_out, int out_size, void* d_ws, size_t ws_size,
                              hipStream_t stream) {
    const float* x    = (const float*)d_in[0];   // [1,T,IN]
    const float* h0   = (const float*)d_in[1];   // [1,T,H]
    const float* edge = (const float*)d_in[2];   // [E,T,T]
    const float* ba   = (const float*)d_in[3];   // [E,H]
    const float* W    = (const float*)d_in[4];   // [E,H,3H]
    const float* uzur = (const float*)d_in[5];   // [H,2H]
    const float* uhm  = (const float*)d_in[6];   // [H,H]
    const float* iw   = (const float*)d_in[7];   // [IN,3H]
    const float* bw   = (const float*)d_in[8];   // [3H]
    float* out = (float*)d_out;

    float* ws = (float*)d_ws;
    float* hbuf    = ws;                          // T*H
    float* basep   = hbuf + (size_t)T * H;        // T*K3
    float* constv  = basep + (size_t)T * K3;      // 256 (pad)
    float* P       = constv + 256;                // E*T*H
    float* partial = P + (size_t)E * T * H;       // E*T*K3
    // total ~27.3 MB of ws

    hipMemcpyAsync(hbuf, h0, sizeof(float) * T * H, hipMemcpyDeviceToDevice, stream);
    const_kernel<<<1, 192, 0, stream>>>(ba, W, bw, constv);
    base_kernel<<<(T * K3) / 256, 256, 0, stream>>>(x, iw, constv, basep);

    for (int it = 0; it < ITER; ++it) {
        bmm_kernel<<<dim3(T / BMM_BM, E), 128, 0, stream>>>(edge, hbuf, P);
        proj_kernel<<<dim3(T / 64, E), 256, 0, stream>>>(P, W, partial);
        gru_kernel<<<T / 16, 256, 0, stream>>>(hbuf, partial, basep, uzur, uhm);
    }
    hipMemcpyAsync(out, hbuf, sizeof(float) * T * H, hipMemcpyDeviceToDevice, stream);
}

// Round 3
// 1232.197 us; speedup vs baseline: 2.1404x; 2.1404x over previous
//
#include <hip/hip_runtime.h>
#include <hip/hip_fp16.h>
#include <math.h>

// GatedGraphXBias: E=12 edge types, T=2048, H=64, IN=128, 10 iterations.
// Round 3: fp16 scaled hi/lo 3-pass MFMA bmm (16x16x32_f16), pre-transposed
// edge in ws, split-K=2 (768 blocks = 3/CU). Dual accumulators undo the
// power-of-2 scaling exactly. fp32 fallback path if ws is too small.

constexpr int T   = 2048;
constexpr int H   = 64;
constexpr int E   = 12;
constexpr int FIN = 128;
constexpr int K3  = 192;   // 3*H
constexpr int ITER = 10;
constexpr int KSPLIT = 2;
constexpr int KSEG = T / KSPLIT;   // 1024

// hi = fp16(SH*a); lo = fp16(SL*(SH*a - hi)); a ~= (hi + lo/SL)/SH, err ~2^-22*|a|
// P = accH/SH^2 + accL/(SH^2*SL)
#define SH   64.0f
#define SL   4096.0f
#define INV_HH (1.0f / 4096.0f)        // 1/SH^2
#define INV_HL (1.0f / 16777216.0f)    // 1/(SH^2*SL)

typedef _Float16 half8 __attribute__((ext_vector_type(8)));
typedef float f32x4 __attribute__((ext_vector_type(4)));

__device__ __forceinline__ float sigmoidf_(float x) {
    return 1.0f / (1.0f + __expf(-x));
}
__device__ __forceinline__ void split16(float a, ushort& hi, ushort& lo) {
    float as = a * SH;
    __half h1 = __float2half(as);
    float r = (as - __half2float(h1)) * SL;
    __half h2 = __float2half(r);
    hi = __half_as_ushort(h1);
    lo = __half_as_ushort(h2);
}

// ---------------- iteration-invariant prep ----------------

// constv[k] = sum_{e,h} ba[e,h]*W[e,h,k] + E*bw[k]   (one block per k)
__global__ __launch_bounds__(256) void const_kernel(const float* __restrict__ ba,
                                                    const float* __restrict__ W,
                                                    const float* __restrict__ bw,
                                                    float* __restrict__ constv) {
    __shared__ float red[256];
    const int k = blockIdx.x;
    const int tid = threadIdx.x;
    float s = 0.0f;
    for (int eh = tid; eh < E * H; eh += 256)
        s += ba[eh] * W[(size_t)eh * K3 + k];
    red[tid] = s;
    __syncthreads();
    for (int off = 128; off > 0; off >>= 1) {
        if (tid < off) red[tid] += red[tid + off];
        __syncthreads();
    }
    if (tid == 0) constv[k] = red[0] + (float)E * bw[k];
}

// base[t,k] = constv[k] + sum_j x[t,j]*iw[j,k]
__global__ __launch_bounds__(256) void base_kernel(const float* __restrict__ x,
                                                   const float* __restrict__ iw,
                                                   const float* __restrict__ constv,
                                                   float* __restrict__ base) {
    int idx = blockIdx.x * 256 + threadIdx.x;
    int t = idx / K3, k = idx % K3;
    float acc = constv[k];
    const float* xr = x + (size_t)t * FIN;
    for (int j = 0; j < FIN; ++j)
        acc = fmaf(xr[j], iw[(size_t)j * K3 + k], acc);
    base[idx] = acc;
}

// edgeT_hi/lo[e][t][s] (scaled fp16) = split(edge[e][s][t]) — one-time
// grid (T/64, T/64, E), block 256
__global__ __launch_bounds__(256) void edgeT_kernel(const float* __restrict__ edge,
                                                    ushort* __restrict__ ehi,
                                                    ushort* __restrict__ elo) {
    __shared__ float til[64][65];
    const int t0 = blockIdx.x * 64;
    const int s0 = blockIdx.y * 64;
    const int e  = blockIdx.z;
    const int tid = threadIdx.x;
    const float* eb = edge + ((size_t)e * T + s0) * T + t0;
    #pragma unroll
    for (int p = 0; p < 4; ++p) {
        int idx = tid + p * 256;
        int r = idx >> 4, c4 = (idx & 15) << 2;       // r = s-local, c = t-local
        float4 v = *reinterpret_cast<const float4*>(eb + (size_t)r * T + c4);
        til[r][c4] = v.x; til[r][c4 + 1] = v.y; til[r][c4 + 2] = v.z; til[r][c4 + 3] = v.w;
    }
    __syncthreads();
    #pragma unroll
    for (int p = 0; p < 2; ++p) {
        int q = tid + p * 256;
        int tt = q >> 3, cs = q & 7;                  // out row t0+tt, s-chunk cs
        ushort hb[8], lb[8];
        #pragma unroll
        for (int j = 0; j < 8; ++j)
            split16(til[cs * 8 + j][tt], hb[j], lb[j]);
        size_t off = ((size_t)e * T + t0 + tt) * T + s0 + cs * 8;
        *reinterpret_cast<uint4*>(ehi + off) = *reinterpret_cast<uint4*>(hb);
        *reinterpret_cast<uint4*>(elo + off) = *reinterpret_cast<uint4*>(lb);
    }
}

// hT_hi/lo[h][t] (scaled fp16) = split(hbuf[t][h]) — per-iteration, tiny
// grid T/64, block 256
__global__ __launch_bounds__(256) void hsplit_kernel(const float* __restrict__ hbuf,
                                                     ushort* __restrict__ hhi,
                                                     ushort* __restrict__ hlo) {
    __shared__ float til[64][65];
    const int t0 = blockIdx.x * 64;
    const int tid = threadIdx.x;
    #pragma unroll
    for (int p = 0; p < 4; ++p) {
        int idx = tid + p * 256;
        int r = idx >> 4, c4 = (idx & 15) << 2;       // r = t-local, c = h
        float4 v = *reinterpret_cast<const float4*>(hbuf + (size_t)(t0 + r) * H + c4);
        til[r][c4] = v.x; til[r][c4 + 1] = v.y; til[r][c4 + 2] = v.z; til[r][c4 + 3] = v.w;
    }
    __syncthreads();
    #pragma unroll
    for (int p = 0; p < 2; ++p) {
        int q = tid + p * 256;
        int hh = q >> 3, cs = q & 7;                  // out row h, t-chunk cs
        ushort hb[8], lb[8];
        #pragma unroll
        for (int j = 0; j < 8; ++j)
            split16(til[cs * 8 + j][hh], hb[j], lb[j]);
        size_t off = (size_t)hh * T + t0 + cs * 8;
        *reinterpret_cast<uint4*>(hhi + off) = *reinterpret_cast<uint4*>(hb);
        *reinterpret_cast<uint4*>(hlo + off) = *reinterpret_cast<uint4*>(lb);
    }
}

// ---------------- MFMA bmm ----------------
// P2[kz][e][t][h] = sum_{s in seg kz} edgeT[e][t][s] * h[s][h]
// grid (T/64, E, KSPLIT), block 256 (4 waves, 2x2 wave grid, 32x32 per wave)
__global__ __launch_bounds__(256) void bmm_mfma_kernel(
        const ushort* __restrict__ Ahi, const ushort* __restrict__ Alo,
        const ushort* __restrict__ Bhi, const ushort* __restrict__ Blo,
        float* __restrict__ P2) {
    __shared__ ushort sAh[64 * 64], sAl[64 * 64], sBh[64 * 64], sBl[64 * 64];
    const int t0 = blockIdx.x * 64;
    const int e  = blockIdx.y;
    const int kz = blockIdx.z;
    const int tid  = threadIdx.x;
    const int lane = tid & 63;
    const int w    = tid >> 6;
    const int wm = w >> 1, wn = w & 1;

    // staging: thread owns chunks q=tid and q=tid+256; q -> (row=q>>3, c=q&7)
    const int r0 = tid >> 3;          // 0..31 (and r0+32)
    const int c0 = tid & 7;
    const int swz = (c0 ^ (r0 & 7)) << 4;             // (r0+32)&7 == r0&7
    const int o0 = r0 * 128 + swz;
    const int o1 = o0 + 32 * 128;

    const size_t ks0 = (size_t)kz * KSEG;
    const ushort* pA0 = Ahi + ((size_t)e * T + t0 + r0) * T + ks0 + c0 * 8;
    const ushort* pA1 = pA0 + (size_t)32 * T;
    const ushort* pL0 = Alo + ((size_t)e * T + t0 + r0) * T + ks0 + c0 * 8;
    const ushort* pL1 = pL0 + (size_t)32 * T;
    const ushort* pB0 = Bhi + (size_t)r0 * T + ks0 + c0 * 8;
    const ushort* pB1 = pB0 + (size_t)32 * T;
    const ushort* pC0 = Blo + (size_t)r0 * T + ks0 + c0 * 8;
    const ushort* pC1 = pC0 + (size_t)32 * T;

    char* bAh = (char*)sAh; char* bAl = (char*)sAl;
    char* bBh = (char*)sBh; char* bBl = (char*)sBl;

    f32x4 accH[2][2], accL[2][2];
    #pragma unroll
    for (int i = 0; i < 2; ++i)
        #pragma unroll
        for (int j = 0; j < 2; ++j) { accH[i][j] = (f32x4)(0.0f); accL[i][j] = (f32x4)(0.0f); }

    for (int kt = 0; kt < KSEG / 64; ++kt) {
        const int ko = kt * 64;
        uint4 va0 = *reinterpret_cast<const uint4*>(pA0 + ko);
        uint4 va1 = *reinterpret_cast<const uint4*>(pA1 + ko);
        uint4 vl0 = *reinterpret_cast<const uint4*>(pL0 + ko);
        uint4 vl1 = *reinterpret_cast<const uint4*>(pL1 + ko);
        uint4 vb0 = *reinterpret_cast<const uint4*>(pB0 + ko);
        uint4 vb1 = *reinterpret_cast<const uint4*>(pB1 + ko);
        uint4 vc0 = *reinterpret_cast<const uint4*>(pC0 + ko);
        uint4 vc1 = *reinterpret_cast<const uint4*>(pC1 + ko);
        __syncthreads();   // previous tile fully consumed
        *reinterpret_cast<uint4*>(bAh + o0) = va0;
        *reinterpret_cast<uint4*>(bAh + o1) = va1;
        *reinterpret_cast<uint4*>(bAl + o0) = vl0;
        *reinterpret_cast<uint4*>(bAl + o1) = vl1;
        *reinterpret_cast<uint4*>(bBh + o0) = vb0;
        *reinterpret_cast<uint4*>(bBh + o1) = vb1;
        *reinterpret_cast<uint4*>(bBl + o0) = vc0;
        *reinterpret_cast<uint4*>(bBl + o1) = vc1;
        __syncthreads();

        half8 fah[2][2], fal[2][2], fbh[2][2], fbl[2][2];
        #pragma unroll
        for (int mi = 0; mi < 2; ++mi)
            #pragma unroll
            for (int kk = 0; kk < 2; ++kk) {
                int row = wm * 32 + mi * 16 + (lane & 15);
                int ch  = kk * 4 + (lane >> 4);
                int off = row * 128 + (((ch ^ (row & 7))) << 4);
                fah[mi][kk] = *reinterpret_cast<const half8*>(bAh + off);
                fal[mi][kk] = *reinterpret_cast<const half8*>(bAl + off);
            }
        #pragma unroll
        for (int ni = 0; ni < 2; ++ni)
            #pragma unroll
            for (int kk = 0; kk < 2; ++kk) {
                int row = wn * 32 + ni * 16 + (lane & 15);
                int ch  = kk * 4 + (lane >> 4);
                int off = row * 128 + (((ch ^ (row & 7))) << 4);
                fbh[ni][kk] = *reinterpret_cast<const half8*>(bBh + off);
                fbl[ni][kk] = *reinterpret_cast<const half8*>(bBl + off);
            }
        #pragma unroll
        for (int mi = 0; mi < 2; ++mi)
            #pragma unroll
            for (int ni = 0; ni < 2; ++ni)
                #pragma unroll
                for (int kk = 0; kk < 2; ++kk) {
                    accH[mi][ni] = __builtin_amdgcn_mfma_f32_16x16x32_f16(
                        fah[mi][kk], fbh[ni][kk], accH[mi][ni], 0, 0, 0);
                    accL[mi][ni] = __builtin_amdgcn_mfma_f32_16x16x32_f16(
                        fah[mi][kk], fbl[ni][kk], accL[mi][ni], 0, 0, 0);
                    accL[mi][ni] = __builtin_amdgcn_mfma_f32_16x16x32_f16(
                        fal[mi][kk], fbh[ni][kk], accL[mi][ni], 0, 0, 0);
                }
    }

    float* outp = P2 + (((size_t)kz * E + e) * T + t0) * H;
    #pragma unroll
    for (int mi = 0; mi < 2; ++mi)
        #pragma unroll
        for (int ni = 0; ni < 2; ++ni)
            #pragma unroll
            for (int j = 0; j < 4; ++j) {
                int row = wm * 32 + mi * 16 + (lane >> 4) * 4 + j;
                int col = wn * 32 + ni * 16 + (lane & 15);
                outp[(size_t)row * H + col] =
                    accH[mi][ni][j] * INV_HH + accL[mi][ni][j] * INV_HL;
            }
}

// ---------------- fp32 fallback bmm (round-1 kernel) ----------------
constexpr int BMM_BM = 64;
constexpr int BMM_BK = 32;
__global__ __launch_bounds__(128) void bmm_kernel(const float* __restrict__ edge,
                                                  const float* __restrict__ hbuf,
                                                  float* __restrict__ P) {
    __shared__ float As[BMM_BK][68];
    __shared__ float Bs[BMM_BK][68];
    const int e  = blockIdx.y;
    const int t0 = blockIdx.x * BMM_BM;
    const int tid = threadIdx.x;
    const int ty = tid >> 4;
    const int tx = tid & 15;
    const float* eb = edge + (size_t)e * T * T;
    float acc[8][4];
    #pragma unroll
    for (int i = 0; i < 8; ++i)
        #pragma unroll
        for (int j = 0; j < 4; ++j) acc[i][j] = 0.0f;
    for (int s0 = 0; s0 < T; s0 += BMM_BK) {
        #pragma unroll
        for (int p = 0; p < 4; ++p) {
            int idx = tid + p * 128;
            int r = idx >> 4, c4 = (idx & 15) << 2;
            *reinterpret_cast<float4*>(&As[r][c4]) =
                *reinterpret_cast<const float4*>(eb + (size_t)(s0 + r) * T + t0 + c4);
            *reinterpret_cast<float4*>(&Bs[r][c4]) =
                *reinterpret_cast<const float4*>(hbuf + (size_t)(s0 + r) * H + c4);
        }
        __syncthreads();
        #pragma unroll
        for (int k = 0; k < BMM_BK; ++k) {
            float a[8], b[4];
            *reinterpret_cast<float4*>(&a[0]) = *reinterpret_cast<const float4*>(&As[k][ty * 8]);
            *reinterpret_cast<float4*>(&a[4]) = *reinterpret_cast<const float4*>(&As[k][ty * 8 + 4]);
            *reinterpret_cast<float4*>(&b[0]) = *reinterpret_cast<const float4*>(&Bs[k][tx * 4]);
            #pragma unroll
            for (int i = 0; i < 8; ++i)
                #pragma unroll
                for (int j = 0; j < 4; ++j)
                    acc[i][j] = fmaf(a[i], b[j], acc[i][j]);
        }
        __syncthreads();
    }
    float* pb = P + ((size_t)e * T + t0) * H;
    #pragma unroll
    for (int i = 0; i < 8; ++i) {
        float4 v = make_float4(acc[i][0], acc[i][1], acc[i][2], acc[i][3]);
        *reinterpret_cast<float4*>(pb + (size_t)(ty * 8 + i) * H + tx * 4) = v;
    }
}

// ---------------- projection ----------------
// partial[e,t,k] = sum_h (sum_kz P2[kz,e,t,h]) * W[e,h,k]
__global__ __launch_bounds__(256) void proj_kernel(const float* __restrict__ P2,
                                                   const float* __restrict__ W,
                                                   float* __restrict__ partial,
                                                   int ksplit) {
    __shared__ float Ps[64][68];
    __shared__ float Ws[H][K3];
    const int e  = blockIdx.y;
    const int t0 = blockIdx.x * 64;
    const int tid = threadIdx.x;
    const float* pb = P2 + ((size_t)e * T + t0) * H;
    const size_t SL2 = (size_t)E * T * H;
    const float* wb = W + (size_t)e * H * K3;
    #pragma unroll
    for (int p = 0; p < 4; ++p) {
        int idx = tid + p * 256;
        int r = idx >> 4, c4 = (idx & 15) << 2;
        float4 v = *reinterpret_cast<const float4*>(pb + (size_t)r * H + c4);
        if (ksplit == 2) {
            float4 u = *reinterpret_cast<const float4*>(pb + SL2 + (size_t)r * H + c4);
            v.x += u.x; v.y += u.y; v.z += u.z; v.w += u.w;
        }
        *reinterpret_cast<float4*>(&Ps[r][c4]) = v;
    }
    #pragma unroll
    for (int p = 0; p < 12; ++p) {
        int idx = tid + p * 256;
        int r = idx / 48, c4 = (idx % 48) << 2;
        *reinterpret_cast<float4*>(&Ws[r][c4]) =
            *reinterpret_cast<const float4*>(wb + (size_t)r * K3 + c4);
    }
    __syncthreads();
    const int ty = tid >> 4;
    const int tx = tid & 15;
    float acc[4][12];
    #pragma unroll
    for (int i = 0; i < 4; ++i)
        #pragma unroll
        for (int c = 0; c < 12; ++c) acc[i][c] = 0.0f;
    for (int h = 0; h < H; ++h) {
        float a[4], b[12];
        #pragma unroll
        for (int i = 0; i < 4; ++i) a[i] = Ps[ty * 4 + i][h];
        *reinterpret_cast<float4*>(&b[0]) = *reinterpret_cast<const float4*>(&Ws[h][tx * 12]);
        *reinterpret_cast<float4*>(&b[4]) = *reinterpret_cast<const float4*>(&Ws[h][tx * 12 + 4]);
        *reinterpret_cast<float4*>(&b[8]) = *reinterpret_cast<const float4*>(&Ws[h][tx * 12 + 8]);
        #pragma unroll
        for (int i = 0; i < 4; ++i)
            #pragma unroll
            for (int c = 0; c < 12; ++c)
                acc[i][c] = fmaf(a[i], b[c], acc[i][c]);
    }
    float* ob = partial + ((size_t)e * T + t0) * K3;
    #pragma unroll
    for (int i = 0; i < 4; ++i) {
        float* orow = ob + (size_t)(ty * 4 + i) * K3 + tx * 12;
        *reinterpret_cast<float4*>(orow)     = make_float4(acc[i][0], acc[i][1], acc[i][2],  acc[i][3]);
        *reinterpret_cast<float4*>(orow + 4) = make_float4(acc[i][4], acc[i][5], acc[i][6],  acc[i][7]);
        *reinterpret_cast<float4*>(orow + 8) = make_float4(acc[i][8], acc[i][9], acc[i][10], acc[i][11]);
    }
}

// ---------------- GRU update ----------------
__global__ __launch_bounds__(256) void gru_kernel(float* __restrict__ hbuf,
                                                  const float* __restrict__ partial,
                                                  const float* __restrict__ base,
                                                  const float* __restrict__ uzur,
                                                  const float* __restrict__ uhm) {
    __shared__ float Uzr[H][2 * H];
    __shared__ float Uh[H][H];
    __shared__ float hrow[16][68];
    __shared__ float rh[16][68];
    const int t0 = blockIdx.x * 16;
    const int tid = threadIdx.x;
    #pragma unroll
    for (int p = 0; p < 8; ++p) {
        int idx = tid + p * 256;
        int r = idx >> 5, c4 = (idx & 31) << 2;
        *reinterpret_cast<float4*>(&Uzr[r][c4]) =
            *reinterpret_cast<const float4*>(uzur + (size_t)r * 2 * H + c4);
    }
    #pragma unroll
    for (int p = 0; p < 4; ++p) {
        int idx = tid + p * 256;
        int r = idx >> 4, c4 = (idx & 15) << 2;
        *reinterpret_cast<float4*>(&Uh[r][c4]) =
            *reinterpret_cast<const float4*>(uhm + (size_t)r * H + c4);
    }
    {
        int r = tid >> 4, c4 = (tid & 15) << 2;
        *reinterpret_cast<float4*>(&hrow[r][c4]) =
            *reinterpret_cast<const float4*>(hbuf + (size_t)(t0 + r) * H + c4);
    }
    __syncthreads();
    const int row = tid >> 4, cg = tid & 15;
    const int t = t0 + row, j0 = cg * 4;

    float az[4], ar[4], ah[4];
    const float* bp = base + (size_t)t * K3;
    {
        float4 b0 = *reinterpret_cast<const float4*>(bp + j0);
        float4 b1 = *reinterpret_cast<const float4*>(bp + 64 + j0);
        float4 b2 = *reinterpret_cast<const float4*>(bp + 128 + j0);
        az[0]=b0.x; az[1]=b0.y; az[2]=b0.z; az[3]=b0.w;
        ar[0]=b1.x; ar[1]=b1.y; ar[2]=b1.z; ar[3]=b1.w;
        ah[0]=b2.x; ah[1]=b2.y; ah[2]=b2.z; ah[3]=b2.w;
    }
    #pragma unroll
    for (int e = 0; e < E; ++e) {
        const float* pp = partial + ((size_t)e * T + t) * K3;
        float4 v0 = *reinterpret_cast<const float4*>(pp + j0);
        float4 v1 = *reinterpret_cast<const float4*>(pp + 64 + j0);
        float4 v2 = *reinterpret_cast<const float4*>(pp + 128 + j0);
        az[0]+=v0.x; az[1]+=v0.y; az[2]+=v0.z; az[3]+=v0.w;
        ar[0]+=v1.x; ar[1]+=v1.y; ar[2]+=v1.z; ar[3]+=v1.w;
        ah[0]+=v2.x; ah[1]+=v2.y; ah[2]+=v2.z; ah[3]+=v2.w;
    }
    float hv[4];
    #pragma unroll
    for (int c = 0; c < 4; ++c) hv[c] = hrow[row][j0 + c];

    float uz[4] = {0,0,0,0}, ur[4] = {0,0,0,0};
    for (int hh = 0; hh < H; ++hh) {
        float hs = hrow[row][hh];
        #pragma unroll
        for (int c = 0; c < 4; ++c) {
            uz[c] = fmaf(hs, Uzr[hh][j0 + c], uz[c]);
            ur[c] = fmaf(hs, Uzr[hh][64 + j0 + c], ur[c]);
        }
    }
    float z[4], rr[4];
    #pragma unroll
    for (int c = 0; c < 4; ++c) {
        z[c]  = sigmoidf_(az[c] + uz[c]);
        rr[c] = sigmoidf_(ar[c] + ur[c]);
        rh[row][j0 + c] = rr[c] * hv[c];
    }
    __syncthreads();
    float uht[4] = {0,0,0,0};
    for (int hh = 0; hh < H; ++hh) {
        float rs = rh[row][hh];
        #pragma unroll
        for (int c = 0; c < 4; ++c)
            uht[c] = fmaf(rs, Uh[hh][j0 + c], uht[c]);
    }
    float hn[4];
    #pragma unroll
    for (int c = 0; c < 4; ++c) {
        float ht = tanhf(ah[c] + uht[c]);
        hn[c] = (1.0f - z[c]) * hv[c] + z[c] * ht;
    }
    *reinterpret_cast<float4*>(hbuf + (size_t)t * H + j0) =
        make_float4(hn[0], hn[1], hn[2], hn[3]);
}

extern "C" void kernel_launch(void* const* d_in, const int* in_sizes, int n_in,
                              void* d_out, int out_size, void* d_ws, size_t ws_size,
                              hipStream_t stream) {
    const float* x    = (const float*)d_in[0];
    const float* h0   = (const float*)d_in[1];
    const float* edge = (const float*)d_in[2];
    const float* ba   = (const float*)d_in[3];
    const float* W    = (const float*)d_in[4];
    const float* uzur = (const float*)d_in[5];
    const float* uhm  = (const float*)d_in[6];
    const float* iw   = (const float*)d_in[7];
    const float* bw   = (const float*)d_in[8];
    float* out = (float*)d_out;

    float* ws = (float*)d_ws;
    float* hbuf    = ws;                                   // T*H
    float* basep   = hbuf + (size_t)T * H;                 // T*K3
    float* constv  = basep + (size_t)T * K3;               // 256
    float* P2      = constv + 256;                         // KSPLIT*E*T*H
    float* partial = P2 + (size_t)KSPLIT * E * T * H;      // E*T*K3
    ushort* hT_hi  = (ushort*)(partial + (size_t)E * T * K3);  // H*T
    ushort* hT_lo  = hT_hi + (size_t)H * T;
    ushort* eT_hi  = hT_lo + (size_t)H * T;                // E*T*T
    ushort* eT_lo  = eT_hi + (size_t)E * T * T;

    const size_t NEED_MFMA =
        (size_t)((char*)(eT_lo + (size_t)E * T * T) - (char*)d_ws);
    const bool useMfma = ws_size >= NEED_MFMA;

    hipMemcpyAsync(hbuf, h0, sizeof(float) * T * H, hipMemcpyDeviceToDevice, stream);
    const_kernel<<<K3, 256, 0, stream>>>(ba, W, bw, constv);
    base_kernel<<<(T * K3) / 256, 256, 0, stream>>>(x, iw, constv, basep);

    if (useMfma) {
        edgeT_kernel<<<dim3(T / 64, T / 64, E), 256, 0, stream>>>(edge, eT_hi, eT_lo);
        for (int it = 0; it < ITER; ++it) {
            hsplit_kernel<<<T / 64, 256, 0, stream>>>(hbuf, hT_hi, hT_lo);
            bmm_mfma_kernel<<<dim3(T / 64, E, KSPLIT), 256, 0, stream>>>(
                eT_hi, eT_lo, hT_hi, hT_lo, P2);
            proj_kernel<<<dim3(T / 64, E), 256, 0, stream>>>(P2, W, partial, 2);
            gru_kernel<<<T / 16, 256, 0, stream>>>(hbuf, partial, basep, uzur, uhm);
        }
    } else {
        for (int it = 0; it < ITER; ++it) {
            bmm_kernel<<<dim3(T / BMM_BM, E), 128, 0, stream>>>(edge, hbuf, P2);
            proj_kernel<<<dim3(T / 64, E), 256, 0, stream>>>(P2, W, partial, 1);
            gru_kernel<<<T / 16, 256, 0, stream>>>(hbuf, partial, basep, uzur, uhm);
        }
    }
    hipMemcpyAsync(out, hbuf, sizeof(float) * T * H, hipMemcpyDeviceToDevice, stream);
}